// Round 1
// baseline (1009.765 us; speedup 1.0000x reference)
//
#include <hip/hip_runtime.h>
#include <hip/hip_bf16.h>

// CGCNN forward, MFMA conv GEMM (R9).
//   g[e,:] = [x[n(e)] | x[nb(e)] | bond(e)] @ Wf + b  (K=169 pad 192, N=128)
// R9 vs R8: conv passes are latency-bound (MfmaUtil 12%, VALU 38%, HBM 10%,
// VGPR=80 -> compiler serialized the 18 A-frag gathers per supertile).
// New conv_pipe<ACT> software-pipelines the PAD path:
//   ACT=0 (stats): full double-buffer, frags for s+1 issued before MFMA(s),
//                  idx prefetched 2 ahead; launch_bounds(256,2) for registers.
//   ACT=1 (act):   frag burst for s+1 issued after MFMA(s), hidden under the
//                  ACT phase; raw s_barrier + lgkmcnt(0) (NOT __syncthreads,
//                  whose implicit vmcnt(0) drain would kill the prefetch).
// Grid fixed at 3000 blocks x 5 supertiles (NSUP=15000). R7 LDS-staging
// fallback kept unchanged for ws_size < 108.5 MB.

#define NATOM 60000
#define MNBR  12
#define F0D   92
#define FBD   41
#define FD    64
#define F2D   128
#define NCRY  2000
#define HD    128
#define NSUP  15000          // 720000 edges / 48
#define GS    132            // gbuf row stride (floats)
#define CGRID 3000           // conv grid; NSUP/CGRID == 5 exactly

// ws layout (float units)
#define OFF_X      0ull          // 3,840,000 f32
#define OFF_XH     3840000ull    // 3,840,000 u16
#define OFF_SUMMED 5760000ull    // 3,840,000 f32
#define OFF_STATS  9600000ull    // sum1[128] sq1[128] sum2[64] sq2[64]
#define OFF_CRYS   9600384ull
#define OFF_CNT    9728384ull
#define OFF_WCONV  9730384ull    // 80,833 f32
#define OFF_WBF    9811220ull    // 73,728 u16 = 36,864 f slots
#define OFF_FLAG   9848084ull
#define WS_NEED_BYTES (9848085ull * 4ull)
#define OFF_BPAD   9848088ull    // 34,560,000 u16 = 17,280,000 f slots (16B aligned)
#define WS_FULL_BYTES ((OFF_BPAD + 17280000ull) * 4ull)   // 108,512,352

// offsets inside wconv
#define W_EMB_O  0
#define B_EMB_O  5888
#define W_FULL_O 5952
#define B_FULL_O 70848
#define G1_O     71232
#define BE1_O    71616
#define G2_O     72000
#define BE2_O    72192
#define W_FC_O   72384
#define B_FC_O   80576
#define W_OUT_O  80704
#define B_OUT_O  80832
#define WC_TOTAL 80833

typedef unsigned short u16;
typedef __attribute__((ext_vector_type(8))) short bf16x8;
typedef __attribute__((ext_vector_type(4))) float f32x4;

__device__ __forceinline__ float bf2f(u16 u){
  union { unsigned int i; float f; } v; v.i = ((unsigned int)u) << 16; return v.f;
}
__device__ __forceinline__ u16 f2bf(float f){
  union { float f; unsigned int i; } v; v.f = f;
  unsigned int x = v.i;
  return (u16)((x + 0x7FFFu + ((x >> 16) & 1u)) >> 16);
}
__device__ __forceinline__ float softplusf_(float x){
  return fmaxf(x, 0.f) + log1pf(expf(-fabsf(x)));
}
__device__ __forceinline__ float softplus_fast(float x){
  return fmaxf(x, 0.f) + __logf(1.f + __expf(-fabsf(x)));
}
__device__ __forceinline__ float sigmoid_fast(float x){
  return __builtin_amdgcn_rcpf(1.f + __expf(-x));
}

__global__ __launch_bounds__(64) void detect_kernel(
    const u16* __restrict__ data, int* __restrict__ flag){
  int tid = threadIdx.x;
  float v = bf2f(data[tid * 2]);
  float av = fabsf(v);
  bool sane = (av > 1e-6f) && (av < 100.f);
  unsigned long long m = __ballot(sane);
  if (tid == 0) *flag = (__popcll(m) >= 32) ? 1 : 0;
}

struct CvtArgs {
  const void* src[12];
  int start[13];
};

__global__ __launch_bounds__(256) void cvt_all_kernel(
    CvtArgs a, float* __restrict__ dst, const int* __restrict__ flag){
  int i = blockIdx.x * 256 + threadIdx.x;
  if (i >= WC_TOTAL) return;
  int r = 0;
  while (i >= a.start[r + 1]) r++;
  int rel = i - a.start[r];
  if (*flag) dst[i] = bf2f(((const u16*)a.src[r])[rel]);
  else       dst[i] = ((const float*)a.src[r])[rel];
}

__global__ __launch_bounds__(256) void build_bfrag(
    const float* __restrict__ wfull, u16* __restrict__ wbf){
  int t = blockIdx.x * 256 + threadIdx.x;
  if (t >= 3 * 6 * 8 * 64) return;
  int lane = t & 63, nt = (t >> 6) & 7, c = (t >> 9) % 6, layer = t / 3072;
  int q = lane >> 4, nloc = lane & 15;
  u16 vals[8];
  #pragma unroll
  for (int i = 0; i < 8; i++){
    int k = c * 32 + q * 8 + i;
    float v = (k < 169) ? wfull[layer * 169 * F2D + k * F2D + nt * 16 + nloc] : 0.f;
    vals[i] = f2bf(v);
  }
  *(uint4*)&wbf[(size_t)t * 8] = *(uint4*)vals;
}

// One-time repack: bond_pad[e][0..47] = bf16(nbr_fea[e][k]) (0 for k>=41).
__global__ __launch_bounds__(256) void bond_prep(
    const void* __restrict__ nbr_fea, u16* __restrict__ bond_pad,
    const int* __restrict__ flag){
  __shared__ __align__(16) char sm[7872];
  u16*   lb_u = (u16*)sm;
  float* lb_f = (float*)sm;
  int s = blockIdx.x, tid = threadIdx.x;
  const int isbf = *flag;
  if (isbf){
    const uint4* src = (const uint4*)((const u16*)nbr_fea + (size_t)s * 1968);
    if (tid < 246) ((uint4*)sm)[tid] = src[tid];
  } else {
    const uint4* src = (const uint4*)((const float*)nbr_fea + (size_t)s * 1968);
    for (int t = tid; t < 492; t += 256) ((uint4*)sm)[t] = src[t];
  }
  __syncthreads();
  uint4* outv = (uint4*)(bond_pad + (size_t)s * 2304);
  for (int slot = tid; slot < 288; slot += 256){
    int el = slot / 6, jj = slot - el * 6;
    u16 v[8];
    #pragma unroll
    for (int i = 0; i < 8; i++){
      int k = jj * 8 + i;
      v[i] = (k < FBD) ? (isbf ? lb_u[el * FBD + k] : f2bf(lb_f[el * FBD + k])) : (u16)0;
    }
    outv[slot] = *(uint4*)v;
  }
}

__global__ __launch_bounds__(256) void embed_kernel(
    const void* __restrict__ atom_fea, const float* __restrict__ W_emb,
    const float* __restrict__ b_emb, float* __restrict__ x,
    u16* __restrict__ xh, const int* __restrict__ flag){
  int tid = threadIdx.x;
  int n = blockIdx.x * 4 + (tid >> 6);
  int f = tid & 63;
  float acc = b_emb[f];
  if (*flag){
    const u16* arow = (const u16*)atom_fea + n * F0D;
    for (int k = 0; k < F0D; k++)
      acc = fmaf(bf2f(arow[k]), W_emb[k * FD + f], acc);
  } else {
    const float* arow = (const float*)atom_fea + n * F0D;
    for (int k = 0; k < F0D; k++)
      acc = fmaf(arow[k], W_emb[k * FD + f], acc);
  }
  x[n * FD + f] = acc;
  xh[n * FD + f] = f2bf(acc);
}

// ---------------------------------------------------------------------------
// R9: software-pipelined conv pass (PAD path). ACT: 0 = BN1 stats only,
// 1 = fused act+sum+BN2 stats. Grid MUST be CGRID; each block runs exactly
// NSUP/CGRID == 5 supertiles.
// ---------------------------------------------------------------------------
template<int ACT>
__global__ __launch_bounds__(256, ACT ? 3 : 2) void conv_pipe(
    const u16* __restrict__ xh, const u16* __restrict__ bond_pad,
    const int* __restrict__ nbr_idx, const u16* __restrict__ wbf_l,
    const float* __restrict__ bfull, const float* __restrict__ sum1,
    const float* __restrict__ sq1, const float* __restrict__ g1,
    const float* __restrict__ be1, float* __restrict__ summed,
    float* __restrict__ o_sum, float* __restrict__ o_sq){
  extern __shared__ char smem[];
  float* gbuf = (float*)smem;                    // ACT only: 48*GS f32
  float* redS = ACT ? (gbuf + 48 * GS) : (float*)smem;
  float* redQ = redS + (ACT ? 64 : 128);

  const int tid = threadIdx.x;
  const int w = tid >> 6, lane = tid & 63;
  const int q = lane >> 4, nloc = lane & 15;

  bf16x8 Bf[6][2];
  const bf16x8* Bv = (const bf16x8*)wbf_l;
  #pragma unroll
  for (int c = 0; c < 6; c++)
    #pragma unroll
    for (int t2 = 0; t2 < 2; t2++)
      Bf[c][t2] = Bv[(c * 8 + w * 2 + t2) * 64 + lane];
  float bias0 = bfull[w * 32 + nloc];
  float bias1 = bfull[w * 32 + 16 + nloc];

  float A0 = 0.f, B0 = 0.f, A1 = 0.f, B1 = 0.f;
  if (ACT){
    const float invR = 1.f / (float)(NATOM * MNBR);
    float m0 = sum1[lane] * invR;
    float v0 = fmaxf(sq1[lane] * invR - m0 * m0, 0.f);
    A0 = g1[lane] * rsqrtf(v0 + 1e-5f);  B0 = be1[lane] - m0 * A0;
    float m1 = sum1[64 + lane] * invR;
    float v1 = fmaxf(sq1[64 + lane] * invR - m1 * m1, 0.f);
    A1 = g1[64 + lane] * rsqrtf(v1 + 1e-5f);  B1 = be1[64 + lane] - m1 * A1;
  }
  float sAcc0 = 0.f, sAcc1 = 0.f, qAcc0 = 0.f, qAcc1 = 0.f;
  if (tid < (ACT ? 64 : 128)){ redS[tid] = 0.f; redQ[tid] = 0.f; }

  const bf16x8* xv = (const bf16x8*)xh;
  const bf16x8 zero8 = {0,0,0,0,0,0,0,0};
  const int s0 = blockIdx.x;

  if (ACT){
    // ---- ACT=1: single-buffer, reload burst after MFMA, raw barriers ----
    int nbp[2][3];
    bf16x8 Axh[3][4], Abd[3][2];
    {
      int e0 = s0 * 48 + nloc;
      nbp[0][0] = nbr_idx[e0];  nbp[0][1] = nbr_idx[e0 + 16];  nbp[0][2] = nbr_idx[e0 + 32];
      int e1 = e0 + CGRID * 48;
      nbp[1][0] = nbr_idx[e1];  nbp[1][1] = nbr_idx[e1 + 16];  nbp[1][2] = nbr_idx[e1 + 32];
    }
    #pragma unroll
    for (int et = 0; et < 3; et++){
      const bf16x8* bpv = (const bf16x8*)(bond_pad + (size_t)(s0 * 48 + et * 16 + nloc) * 48);
      Abd[et][0] = bpv[q];
      Abd[et][1] = (q < 2) ? bpv[4 + q] : zero8;
      int na = s0 * 4 + (et * 16 + nloc) / 12;
      int nb = nbp[0][et];
      Axh[et][0] = xv[na * 8 + q];      Axh[et][1] = xv[na * 8 + 4 + q];
      Axh[et][2] = xv[nb * 8 + q];      Axh[et][3] = xv[nb * 8 + 4 + q];
    }
    #pragma unroll
    for (int k = 0; k < 5; k++){
      const int s = s0 + k * CGRID;
      // MFMA phase (bond frags consumed first so their regs die early)
      #pragma unroll
      for (int et = 0; et < 3; et++){
        #pragma unroll
        for (int t2 = 0; t2 < 2; t2++){
          float bs = t2 ? bias1 : bias0;
          f32x4 acc = {bs, bs, bs, bs};
          acc = __builtin_amdgcn_mfma_f32_16x16x32_bf16(Abd[et][0], Bf[4][t2], acc, 0, 0, 0);
          acc = __builtin_amdgcn_mfma_f32_16x16x32_bf16(Abd[et][1], Bf[5][t2], acc, 0, 0, 0);
          acc = __builtin_amdgcn_mfma_f32_16x16x32_bf16(Axh[et][0], Bf[0][t2], acc, 0, 0, 0);
          acc = __builtin_amdgcn_mfma_f32_16x16x32_bf16(Axh[et][1], Bf[1][t2], acc, 0, 0, 0);
          acc = __builtin_amdgcn_mfma_f32_16x16x32_bf16(Axh[et][2], Bf[2][t2], acc, 0, 0, 0);
          acc = __builtin_amdgcn_mfma_f32_16x16x32_bf16(Axh[et][3], Bf[3][t2], acc, 0, 0, 0);
          int col = w * 32 + t2 * 16 + nloc;
          int r0 = et * 16 + q * 4;
          gbuf[(r0 + 0) * GS + col] = acc[0];
          gbuf[(r0 + 1) * GS + col] = acc[1];
          gbuf[(r0 + 2) * GS + col] = acc[2];
          gbuf[(r0 + 3) * GS + col] = acc[3];
        }
      }
      // prefetch burst for k+1 — stays in flight across the raw barriers,
      // hidden under the ACT phase below
      if (k < 4){
        const int sn = s + CGRID;
        #pragma unroll
        for (int et = 0; et < 3; et++){
          const bf16x8* bpv = (const bf16x8*)(bond_pad + (size_t)(sn * 48 + et * 16 + nloc) * 48);
          Abd[et][0] = bpv[q];
          Abd[et][1] = (q < 2) ? bpv[4 + q] : zero8;
          int na = sn * 4 + (et * 16 + nloc) / 12;
          int nb = nbp[(k + 1) & 1][et];
          Axh[et][0] = xv[na * 8 + q];      Axh[et][1] = xv[na * 8 + 4 + q];
          Axh[et][2] = xv[nb * 8 + q];      Axh[et][3] = xv[nb * 8 + 4 + q];
        }
        if (k < 3){
          int e2 = (s + 2 * CGRID) * 48 + nloc;
          nbp[k & 1][0] = nbr_idx[e2];
          nbp[k & 1][1] = nbr_idx[e2 + 16];
          nbp[k & 1][2] = nbr_idx[e2 + 32];
        }
      }
      // raw barrier: wait only LDS ops (gbuf writes), keep global prefetch
      // in flight (plain __syncthreads would drain vmcnt(0))
      asm volatile("s_waitcnt lgkmcnt(0)" ::: "memory");
      __builtin_amdgcn_s_barrier();
      __builtin_amdgcn_sched_barrier(0);
      float p = 0.f;
      #pragma unroll
      for (int m = 0; m < 12; m++){
        int el = w * 12 + m;
        float u = fmaf(gbuf[el * GS + lane],      A0, B0);
        float v = fmaf(gbuf[el * GS + 64 + lane], A1, B1);
        p = fmaf(sigmoid_fast(u), softplus_fast(v), p);
      }
      summed[(s * 4 + w) * 64 + lane] = p;
      sAcc0 += p;  qAcc0 = fmaf(p, p, qAcc0);
      // protect gbuf for next iteration (LDS reads done)
      asm volatile("s_waitcnt lgkmcnt(0)" ::: "memory");
      __builtin_amdgcn_s_barrier();
      __builtin_amdgcn_sched_barrier(0);
    }
  } else {
    // ---- ACT=0: barrier-free, full double-buffer, prefetch before MFMA ----
    int nbp[2][3];
    bf16x8 Axh[2][3][4], Abd[2][3][2];
    {
      int e0 = s0 * 48 + nloc;
      nbp[0][0] = nbr_idx[e0];  nbp[0][1] = nbr_idx[e0 + 16];  nbp[0][2] = nbr_idx[e0 + 32];
      int e1 = e0 + CGRID * 48;
      nbp[1][0] = nbr_idx[e1];  nbp[1][1] = nbr_idx[e1 + 16];  nbp[1][2] = nbr_idx[e1 + 32];
    }
    #pragma unroll
    for (int et = 0; et < 3; et++){
      const bf16x8* bpv = (const bf16x8*)(bond_pad + (size_t)(s0 * 48 + et * 16 + nloc) * 48);
      Abd[0][et][0] = bpv[q];
      Abd[0][et][1] = (q < 2) ? bpv[4 + q] : zero8;
      int na = s0 * 4 + (et * 16 + nloc) / 12;
      int nb = nbp[0][et];
      Axh[0][et][0] = xv[na * 8 + q];   Axh[0][et][1] = xv[na * 8 + 4 + q];
      Axh[0][et][2] = xv[nb * 8 + q];   Axh[0][et][3] = xv[nb * 8 + 4 + q];
    }
    #pragma unroll
    for (int k = 0; k < 5; k++){
      const int cur = k & 1, nxt = cur ^ 1;
      const int s = s0 + k * CGRID;
      if (k < 4){
        const int sn = s + CGRID;
        #pragma unroll
        for (int et = 0; et < 3; et++){
          const bf16x8* bpv = (const bf16x8*)(bond_pad + (size_t)(sn * 48 + et * 16 + nloc) * 48);
          Abd[nxt][et][0] = bpv[q];
          Abd[nxt][et][1] = (q < 2) ? bpv[4 + q] : zero8;
          int na = sn * 4 + (et * 16 + nloc) / 12;
          int nb = nbp[nxt][et];
          Axh[nxt][et][0] = xv[na * 8 + q];   Axh[nxt][et][1] = xv[na * 8 + 4 + q];
          Axh[nxt][et][2] = xv[nb * 8 + q];   Axh[nxt][et][3] = xv[nb * 8 + 4 + q];
        }
        if (k < 3){
          int e2 = (s + 2 * CGRID) * 48 + nloc;
          nbp[cur][0] = nbr_idx[e2];
          nbp[cur][1] = nbr_idx[e2 + 16];
          nbp[cur][2] = nbr_idx[e2 + 32];
        }
      }
      #pragma unroll
      for (int et = 0; et < 3; et++){
        #pragma unroll
        for (int t2 = 0; t2 < 2; t2++){
          float bs = t2 ? bias1 : bias0;
          f32x4 acc = {bs, bs, bs, bs};
          acc = __builtin_amdgcn_mfma_f32_16x16x32_bf16(Abd[cur][et][0], Bf[4][t2], acc, 0, 0, 0);
          acc = __builtin_amdgcn_mfma_f32_16x16x32_bf16(Abd[cur][et][1], Bf[5][t2], acc, 0, 0, 0);
          acc = __builtin_amdgcn_mfma_f32_16x16x32_bf16(Axh[cur][et][0], Bf[0][t2], acc, 0, 0, 0);
          acc = __builtin_amdgcn_mfma_f32_16x16x32_bf16(Axh[cur][et][1], Bf[1][t2], acc, 0, 0, 0);
          acc = __builtin_amdgcn_mfma_f32_16x16x32_bf16(Axh[cur][et][2], Bf[2][t2], acc, 0, 0, 0);
          acc = __builtin_amdgcn_mfma_f32_16x16x32_bf16(Axh[cur][et][3], Bf[3][t2], acc, 0, 0, 0);
          float ss = acc[0] + acc[1] + acc[2] + acc[3];
          float qq = acc[0]*acc[0] + acc[1]*acc[1] + acc[2]*acc[2] + acc[3]*acc[3];
          if (t2){ sAcc1 += ss; qAcc1 += qq; } else { sAcc0 += ss; qAcc0 += qq; }
        }
      }
    }
  }

  __syncthreads();
  if (ACT){
    atomicAdd(&redS[lane], sAcc0);
    atomicAdd(&redQ[lane], qAcc0);
    __syncthreads();
    if (tid < 64){ atomicAdd(&o_sum[tid], redS[tid]); atomicAdd(&o_sq[tid], redQ[tid]); }
  } else {
    int c0 = w * 32 + nloc;
    atomicAdd(&redS[c0], sAcc0);       atomicAdd(&redQ[c0], qAcc0);
    atomicAdd(&redS[c0 + 16], sAcc1);  atomicAdd(&redQ[c0 + 16], qAcc1);
    __syncthreads();
    if (tid < 128){ atomicAdd(&o_sum[tid], redS[tid]); atomicAdd(&o_sq[tid], redQ[tid]); }
  }
}

// R7 fallback conv pass (only instantiated for PAD=0, small-ws path).
template<int ACT, int PAD>
__global__ __launch_bounds__(256, 3) void conv_mfma(
    const u16* __restrict__ xh, const void* __restrict__ nbr_fea,
    const u16* __restrict__ bond_pad,
    const int* __restrict__ nbr_idx, const u16* __restrict__ wbf_l,
    const float* __restrict__ bfull, const float* __restrict__ sum1,
    const float* __restrict__ sq1, const float* __restrict__ g1,
    const float* __restrict__ be1, float* __restrict__ summed,
    float* __restrict__ o_sum, float* __restrict__ o_sq,
    const int* __restrict__ flag){
  extern __shared__ char smem[];
  u16*   fragA = (u16*)smem;                      // PAD=0 only: 6*512 u16
  const int base_off = PAD ? 0 : 6144;
  float* gbuf  = (float*)(smem + base_off);       // ACT only: 48*GS
  float* redS  = ACT ? (gbuf + 48 * GS) : (float*)(smem + base_off);
  float* redQ  = redS + (ACT ? 64 : 128);

  const int tid = threadIdx.x;
  const int w = tid >> 6, lane = tid & 63;
  const int q = lane >> 4, nloc = lane & 15, q8 = q * 8;
  const int isbf = *flag;

  bf16x8 Bf[6][2];
  const bf16x8* Bv = (const bf16x8*)wbf_l;
  #pragma unroll
  for (int c = 0; c < 6; c++)
    #pragma unroll
    for (int t2 = 0; t2 < 2; t2++)
      Bf[c][t2] = Bv[(c * 8 + w * 2 + t2) * 64 + lane];
  float bias0 = bfull[w * 32 + nloc];
  float bias1 = bfull[w * 32 + 16 + nloc];

  float A0 = 0.f, B0 = 0.f, A1 = 0.f, B1 = 0.f;
  if (ACT){
    const float invR = 1.f / (float)(NATOM * MNBR);
    float m0 = sum1[lane] * invR;
    float v0 = fmaxf(sq1[lane] * invR - m0 * m0, 0.f);
    A0 = g1[lane] * rsqrtf(v0 + 1e-5f);  B0 = be1[lane] - m0 * A0;
    float m1 = sum1[64 + lane] * invR;
    float v1 = fmaxf(sq1[64 + lane] * invR - m1 * m1, 0.f);
    A1 = g1[64 + lane] * rsqrtf(v1 + 1e-5f);  B1 = be1[64 + lane] - m1 * A1;
  }
  float sAcc0 = 0.f, sAcc1 = 0.f, qAcc0 = 0.f, qAcc1 = 0.f;
  if (tid < (ACT ? 64 : 128)){ redS[tid] = 0.f; redQ[tid] = 0.f; }

  const bf16x8* xv = (const bf16x8*)xh;
  const bf16x8 zero8 = {0,0,0,0,0,0,0,0};
  for (int s = blockIdx.x; s < NSUP; s += gridDim.x){
    int e0 = s * 48 + nloc;
    int nb0 = nbr_idx[e0], nb1 = nbr_idx[e0 + 16], nb2 = nbr_idx[e0 + 32];
    bf16x8 Af[3][6];
    if (PAD){
      #pragma unroll
      for (int et = 0; et < 3; et++){
        int nb = (et == 0) ? nb0 : (et == 1) ? nb1 : nb2;
        int na = s * 4 + (et * 16 + nloc) / 12;
        Af[et][0] = xv[na * 8 + q];
        Af[et][1] = xv[na * 8 + 4 + q];
        Af[et][2] = xv[nb * 8 + q];
        Af[et][3] = xv[nb * 8 + 4 + q];
        const bf16x8* bpv = (const bf16x8*)(bond_pad + (size_t)(e0 + et * 16) * 48);
        Af[et][4] = bpv[q];
        Af[et][5] = (q < 2) ? bpv[4 + q] : zero8;
      }
    } else {
      if (w < 3){
        size_t eg = (size_t)(s * 48 + w * 16 + nloc);
        u16 v4[8], v5[8];
        if (isbf){
          const u16* br = (const u16*)nbr_fea + eg * 41;
          #pragma unroll
          for (int i = 0; i < 8; i++) v4[i] = br[q8 + i];
          #pragma unroll
          for (int i = 0; i < 8; i++){
            int k5 = 32 + q8 + i;
            v5[i] = (k5 < 41) ? br[k5] : (u16)0;
          }
        } else {
          const float* br = (const float*)nbr_fea + eg * 41;
          #pragma unroll
          for (int i = 0; i < 8; i++) v4[i] = f2bf(br[q8 + i]);
          #pragma unroll
          for (int i = 0; i < 8; i++){
            int k5 = 32 + q8 + i;
            v5[i] = (k5 < 41) ? f2bf(br[k5]) : (u16)0;
          }
        }
        *(uint4*)&fragA[(w * 2 + 0) * 512 + lane * 8] = *(uint4*)v4;
        *(uint4*)&fragA[(w * 2 + 1) * 512 + lane * 8] = *(uint4*)v5;
      }
      __syncthreads();
      #pragma unroll
      for (int et = 0; et < 3; et++){
        int nb = (et == 0) ? nb0 : (et == 1) ? nb1 : nb2;
        int na = s * 4 + (et * 16 + nloc) / 12;
        Af[et][0] = xv[na * 8 + q];
        Af[et][1] = xv[na * 8 + 4 + q];
        Af[et][2] = xv[nb * 8 + q];
        Af[et][3] = xv[nb * 8 + 4 + q];
        Af[et][4] = *(bf16x8*)&fragA[(et * 2 + 0) * 512 + lane * 8];
        Af[et][5] = *(bf16x8*)&fragA[(et * 2 + 1) * 512 + lane * 8];
      }
    }
    #pragma unroll
    for (int et = 0; et < 3; et++){
      #pragma unroll
      for (int t2 = 0; t2 < 2; t2++){
        float bs = t2 ? bias1 : bias0;
        f32x4 acc = {bs, bs, bs, bs};
        acc = __builtin_amdgcn_mfma_f32_16x16x32_bf16(Af[et][0], Bf[0][t2], acc, 0, 0, 0);
        acc = __builtin_amdgcn_mfma_f32_16x16x32_bf16(Af[et][1], Bf[1][t2], acc, 0, 0, 0);
        acc = __builtin_amdgcn_mfma_f32_16x16x32_bf16(Af[et][2], Bf[2][t2], acc, 0, 0, 0);
        acc = __builtin_amdgcn_mfma_f32_16x16x32_bf16(Af[et][3], Bf[3][t2], acc, 0, 0, 0);
        acc = __builtin_amdgcn_mfma_f32_16x16x32_bf16(Af[et][4], Bf[4][t2], acc, 0, 0, 0);
        acc = __builtin_amdgcn_mfma_f32_16x16x32_bf16(Af[et][5], Bf[5][t2], acc, 0, 0, 0);
        if (ACT){
          int col = w * 32 + t2 * 16 + nloc;
          int r0 = et * 16 + q * 4;
          gbuf[(r0 + 0) * GS + col] = acc[0];
          gbuf[(r0 + 1) * GS + col] = acc[1];
          gbuf[(r0 + 2) * GS + col] = acc[2];
          gbuf[(r0 + 3) * GS + col] = acc[3];
        } else {
          float ss = acc[0] + acc[1] + acc[2] + acc[3];
          float qq = acc[0]*acc[0] + acc[1]*acc[1] + acc[2]*acc[2] + acc[3]*acc[3];
          if (t2){ sAcc1 += ss; qAcc1 += qq; } else { sAcc0 += ss; qAcc0 += qq; }
        }
      }
    }
    if (ACT){
      __syncthreads();   // g complete
      float p = 0.f;
      #pragma unroll
      for (int m = 0; m < 12; m++){
        int el = w * 12 + m;
        float u = fmaf(gbuf[el * GS + lane],      A0, B0);
        float v = fmaf(gbuf[el * GS + 64 + lane], A1, B1);
        p = fmaf(sigmoid_fast(u), softplus_fast(v), p);
      }
      summed[(s * 4 + w) * 64 + lane] = p;
      sAcc0 += p;  qAcc0 = fmaf(p, p, qAcc0);
      __syncthreads();   // protect gbuf for next iteration
    } else if (!PAD){
      __syncthreads();   // protect fragA
    }
  }
  __syncthreads();
  if (ACT){
    atomicAdd(&redS[lane], sAcc0);
    atomicAdd(&redQ[lane], qAcc0);
    __syncthreads();
    if (tid < 64){ atomicAdd(&o_sum[tid], redS[tid]); atomicAdd(&o_sq[tid], redQ[tid]); }
  } else {
    int c0 = w * 32 + nloc;
    atomicAdd(&redS[c0], sAcc0);       atomicAdd(&redQ[c0], qAcc0);
    atomicAdd(&redS[c0 + 16], sAcc1);  atomicAdd(&redQ[c0 + 16], qAcc1);
    __syncthreads();
    if (tid < 128){ atomicAdd(&o_sum[tid], redS[tid]); atomicAdd(&o_sq[tid], redQ[tid]); }
  }
}

__global__ __launch_bounds__(256) void update_x_kernel(
    float* __restrict__ x, u16* __restrict__ xh,
    const float* __restrict__ summed,
    const float* __restrict__ sum2, const float* __restrict__ sq2,
    const float* __restrict__ g2, const float* __restrict__ be2){
  int idx = blockIdx.x * 256 + threadIdx.x;
  int f = idx & 63;
  const float invN = 1.f / (float)NATOM;
  float mean = sum2[f] * invN;
  float var  = fmaxf(sq2[f] * invN - mean * mean, 0.f);
  float a = g2[f] * rsqrtf(var + 1e-5f);
  float b = be2[f] - mean * a;
  float v = x[idx] + fmaf(summed[idx], a, b);
  float r = softplusf_(v);
  x[idx] = r;
  xh[idx] = f2bf(r);
}

__global__ __launch_bounds__(256) void pool_kernel(
    const float* __restrict__ x, const int* __restrict__ cidx,
    float* __restrict__ crys, float* __restrict__ cnt){
  int idx = blockIdx.x * 256 + threadIdx.x;
  int n = idx >> 6, f = idx & 63;
  int c = cidx[n];
  atomicAdd(&crys[c * FD + f], x[idx]);
  if (f == 0) atomicAdd(&cnt[c], 1.f);
}

__global__ __launch_bounds__(128) void head_kernel(
    const float* __restrict__ crys, const float* __restrict__ cnt,
    const float* __restrict__ W_fc, const float* __restrict__ b_fc,
    const float* __restrict__ W_out, const float* __restrict__ b_out,
    void* __restrict__ out, const int* __restrict__ flag){
  __shared__ float p_s[FD];
  __shared__ float red_s[HD];
  int c = blockIdx.x, tid = threadIdx.x;
  if (tid < FD){
    float ct = fmaxf(cnt[c], 1.f);
    p_s[tid] = softplusf_(crys[c * FD + tid] / ct);
  }
  __syncthreads();
  float acc = b_fc[tid];
  for (int k = 0; k < FD; k++)
    acc = fmaf(p_s[k], W_fc[k * HD + tid], acc);
  float h = softplusf_(acc);
  red_s[tid] = h * W_out[tid];
  __syncthreads();
  for (int s = HD / 2; s > 0; s >>= 1){
    if (tid < s) red_s[tid] += red_s[tid + s];
    __syncthreads();
  }
  if (tid == 0){
    float r = red_s[0] + b_out[0];
    if (*flag) ((u16*)out)[c] = f2bf(r);
    else       ((float*)out)[c] = r;
  }
}

extern "C" void kernel_launch(void* const* d_in, const int* in_sizes, int n_in,
                              void* d_out, int out_size, void* d_ws, size_t ws_size,
                              hipStream_t stream){
  if (ws_size < WS_NEED_BYTES) return;  // diagnostic: leaves d_out zeroed
  const bool full = (ws_size >= WS_FULL_BYTES);
  const void* atom_fea = d_in[0];
  const void* nbr_fea  = d_in[1];
  const int* nbr_idx   = (const int*)d_in[2];
  const int* cidx      = (const int*)d_in[3];

  float* ws     = (float*)d_ws;
  float* x      = ws + OFF_X;
  u16*   xh     = (u16*)(ws + OFF_XH);
  float* summed = ws + OFF_SUMMED;
  float* sum1   = ws + OFF_STATS;
  float* sq1    = sum1 + 128;
  float* sum2   = sq1 + 128;
  float* sq2    = sum2 + 64;
  float* crys   = ws + OFF_CRYS;
  float* cnt    = ws + OFF_CNT;
  float* wc     = ws + OFF_WCONV;
  u16*   wbf    = (u16*)(ws + OFF_WBF);
  int*   flag   = (int*)(ws + OFF_FLAG);
  u16*   bpad   = (u16*)(ws + OFF_BPAD);

  detect_kernel<<<1, 64, 0, stream>>>((const u16*)nbr_fea, flag);
  CvtArgs ca;
  const int srcidx[12] = {4,5,6,7,8,9,10,11,12,13,14,15};
  const int starts[13] = {W_EMB_O, B_EMB_O, W_FULL_O, B_FULL_O, G1_O, BE1_O,
                          G2_O, BE2_O, W_FC_O, B_FC_O, W_OUT_O, B_OUT_O, WC_TOTAL};
  for (int i = 0; i < 12; i++){ ca.src[i] = d_in[srcidx[i]]; ca.start[i] = starts[i]; }
  ca.start[12] = WC_TOTAL;
  cvt_all_kernel<<<(WC_TOTAL + 255) / 256, 256, 0, stream>>>(ca, wc, flag);
  build_bfrag<<<(9216 + 255) / 256, 256, 0, stream>>>(wc + W_FULL_O, wbf);
  if (full) bond_prep<<<NSUP, 256, 0, stream>>>(nbr_fea, bpad, flag);

  embed_kernel<<<NATOM / 4, 256, 0, stream>>>(atom_fea, wc + W_EMB_O, wc + B_EMB_O,
                                              x, xh, flag);
  const int LDS_STATS_P = 2 * 128 * 4;                   // 1024
  const int LDS_ACT_P   = (48 * GS + 128) * 4;           // 25856
  const int LDS_STATS_F = 6144 + 2 * 128 * 4;            // 7168
  const int LDS_ACT_F   = 6144 + (48 * GS + 128) * 4;    // 32000
  for (int i = 0; i < 3; i++){
    const u16* wbf_l = wbf + (size_t)i * 3072 * 8;
    hipMemsetAsync(sum1, 0, 384 * sizeof(float), stream);
    if (full){
      conv_pipe<0><<<CGRID, 256, LDS_STATS_P, stream>>>(xh, bpad, nbr_idx,
          wbf_l, wc + B_FULL_O + i * F2D, sum1, sq1, wc + G1_O + i * F2D,
          wc + BE1_O + i * F2D, summed, sum1, sq1);
      conv_pipe<1><<<CGRID, 256, LDS_ACT_P, stream>>>(xh, bpad, nbr_idx,
          wbf_l, wc + B_FULL_O + i * F2D, sum1, sq1, wc + G1_O + i * F2D,
          wc + BE1_O + i * F2D, summed, sum2, sq2);
    } else {
      conv_mfma<0,0><<<CGRID, 256, LDS_STATS_F, stream>>>(xh, nbr_fea, bpad, nbr_idx,
          wbf_l, wc + B_FULL_O + i * F2D, sum1, sq1, wc + G1_O + i * F2D,
          wc + BE1_O + i * F2D, summed, sum1, sq1, flag);
      conv_mfma<1,0><<<CGRID, 256, LDS_ACT_F, stream>>>(xh, nbr_fea, bpad, nbr_idx,
          wbf_l, wc + B_FULL_O + i * F2D, sum1, sq1, wc + G1_O + i * F2D,
          wc + BE1_O + i * F2D, summed, sum2, sq2, flag);
    }
    update_x_kernel<<<(NATOM * FD) / 256, 256, 0, stream>>>(x, xh, summed, sum2, sq2,
        wc + G2_O + i * FD, wc + BE2_O + i * FD);
  }
  hipMemsetAsync(crys, 0, (NCRY * FD + NCRY) * sizeof(float), stream);
  pool_kernel<<<(NATOM * FD) / 256, 256, 0, stream>>>(x, cidx, crys, cnt);
  head_kernel<<<NCRY, 128, 0, stream>>>(crys, cnt, wc + W_FC_O, wc + B_FC_O,
      wc + W_OUT_O, wc + B_OUT_O, d_out, flag);
}